// Round 7
// baseline (123.683 us; speedup 1.0000x reference)
//
#include <hip/hip_runtime.h>
#include <hip/hip_bf16.h>

#define NN 4096
#define FF 128
#define CAP 24            // edges per row per 128-col window (lambda=2.56, P(>=24)~1e-15)

__device__ __forceinline__ float bfhi(unsigned int u) { return __uint_as_float(u & 0xFFFF0000u); }
__device__ __forceinline__ float bflo(unsigned int u) { return __uint_as_float(u << 16); }

// ---------------------------------------------------------------------------
// Detect adjacency encoding. bit1 -> float32 ; else bit0 -> uint8 ; else int32.
__global__ __launch_bounds__(256) void detect_fmt(const unsigned int* __restrict__ w,
                                                  int nwords, int* __restrict__ flag) {
    unsigned int hi = 0u, fl = 0u;
    for (int idx = blockIdx.x * blockDim.x + threadIdx.x; idx < nwords;
         idx += gridDim.x * blockDim.x) {
        unsigned int v = w[idx];
        hi |= (v & 0xFFFFFF00u);
        fl |= (v == 0x3F800000u) ? 1u : 0u;
    }
    int bits = (hi ? 1 : 0) | (fl ? 2 : 0);
    if (bits) atomicOr(flag, bits);
}

// ---------------------------------------------------------------------------
// h = x @ W^T, emitted ONLY as bf16 (hbf). attn coefficients fused here from
// the f32 accumulators (better precision than a bf16 round-trip):
//   asrc[i,h] = sum_c h[i,c]*a_src_flat[c],  c in head h's 32-col range.
__global__ __launch_bounds__(256) void gemm_h(const float* __restrict__ x,
                                              const float* __restrict__ W,
                                              const float* __restrict__ a_src,
                                              const float* __restrict__ a_dst,
                                              unsigned short* __restrict__ hbf,
                                              float* __restrict__ asrc,
                                              float* __restrict__ adst) {
    __shared__ float xs[16][FF];
    int r0 = blockIdx.x * 16;
    const float4* xv = (const float4*)(x + (size_t)r0 * FF);
    float4* xsv = (float4*)&xs[0][0];
    for (int t = threadIdx.x; t < 16 * FF / 4; t += 256) xsv[t] = xv[t];
    __syncthreads();

    int c  = threadIdx.x & 127;
    int rr = threadIdx.x >> 7;
    float af = a_src[c];          // [HEADS][D] flat == [c]
    float df = a_dst[c];
    float acc[8] = {0.f, 0.f, 0.f, 0.f, 0.f, 0.f, 0.f, 0.f};
    for (int k = 0; k < FF; k += 4) {
        float4 w4 = *(const float4*)&W[(size_t)c * FF + k];
#pragma unroll
        for (int r8 = 0; r8 < 8; ++r8) {
            float4 x4 = *(const float4*)&xs[rr + r8 * 2][k];
            acc[r8] += w4.x * x4.x + w4.y * x4.y + w4.z * x4.z + w4.w * x4.w;
        }
    }
    float ps[8], pd[8];
#pragma unroll
    for (int r8 = 0; r8 < 8; ++r8) {
        union { __hip_bfloat16 b; unsigned short s; } cv;
        cv.b = __float2bfloat16(acc[r8]);
        hbf[(size_t)(r0 + rr + r8 * 2) * FF + c] = cv.s;
        ps[r8] = acc[r8] * af;
        pd[r8] = acc[r8] * df;
    }
#pragma unroll
    for (int m = 1; m <= 16; m <<= 1) {     // reduce within each 32-lane head group
#pragma unroll
        for (int r8 = 0; r8 < 8; ++r8) {
            ps[r8] += __shfl_xor(ps[r8], m);
            pd[r8] += __shfl_xor(pd[r8], m);
        }
    }
    if ((threadIdx.x & 31) == 0) {
        int hd = c >> 5;
#pragma unroll
        for (int r8 = 0; r8 < 8; ++r8) {
            asrc[(size_t)(r0 + rr + r8 * 2) * 4 + hd] = ps[r8];
            adst[(size_t)(r0 + rr + r8 * 2) * 4 + hd] = pd[r8];
        }
    }
}

// ---------------------------------------------------------------------------
// Sparse GAT aggregation with LDS-staged h windows.
// Grid = 64 i-tiles(64 rows) x 8 j-chunks(512 cols). Block = 512 thr = 8 waves
// = 32 groups-of-16; group owns 2 rows. Loop over 4 windows of 128 j:
//   stage hbf[window] (32KB) + adst[window] (2KB) into LDS (coalesced streams)
//   pass A: 2 lanes/row compact adj-slice nonzeros into per-row ushort lists
//   edge loop: per edge, ALL-LDS: idx u16 + adst dword + h row b128; p=exp(
//   lrelu(sa+dv)) (no max-subtraction: e~N(0,2), far from f32 range); 8 fma.
// Accumulators persist across windows; partial num/den -> ws; combine reduces.
__global__ __launch_bounds__(512, 6) void gat_chunk(const unsigned short* __restrict__ hbf,
                                                    const float* __restrict__ asrc,
                                                    const float* __restrict__ adst,
                                                    const void* __restrict__ adj,
                                                    const int* __restrict__ flag,
                                                    float* __restrict__ num_ws,
                                                    float* __restrict__ den_ws) {
    __shared__ unsigned short sH[128 * FF];        // 32 KB: window rows x feats
    __shared__ unsigned short s_idx[64][CAP];      // 3 KB
    __shared__ unsigned char  s_cnt[64];
    __shared__ float s_adst[128 * 4];              // 2 KB
    __shared__ float s_asrc[64 * 4];               // 1 KB

    const int t   = threadIdx.x;
    const int it  = blockIdx.x >> 3;
    const int jc  = blockIdx.x & 7;
    const int i0  = it * 64;
    const int jb  = jc * 512;
    const int fmt = *flag;                         // 0:int32 1:uint8 2/3:float32

    if (t < 64) *(float4*)&s_asrc[t * 4] = *(const float4*)&asrc[(size_t)(i0 + t) * 4];

    const int g = t >> 4, l16 = t & 15, head = l16 >> 2;
    float acc[2][8];
    float den[2] = {0.f, 0.f};
#pragma unroll
    for (int r2 = 0; r2 < 2; ++r2)
#pragma unroll
        for (int k = 0; k < 8; ++k) acc[r2][k] = 0.f;

    for (int s = 0; s < 4; ++s) {
        const int jbs = jb + s * 128;
        // ---- stage h window + adst window ----
        {
            const uint4* src = (const uint4*)(hbf + (size_t)jbs * FF);
            uint4* dst = (uint4*)sH;
#pragma unroll
            for (int k = 0; k < 4; ++k) dst[t + k * 512] = src[t + k * 512];
        }
        if (t < 128) ((float4*)s_adst)[t] = ((const float4*)(adst + (size_t)jbs * 4))[t];

        // ---- pass A: compact adj slice ----
        if (fmt == 1) {
            if (t < 128) {
                int row = t >> 1, half = t & 1;
                const uint4* ap = (const uint4*)((const unsigned char*)adj +
                                  (size_t)(i0 + row) * NN + jbs + half * 64);
                uint4 v[4];
                int cl = 0;
#pragma unroll
                for (int k2 = 0; k2 < 4; ++k2) {
                    v[k2] = ap[k2];
                    unsigned int vw[4] = {v[k2].x, v[k2].y, v[k2].z, v[k2].w};
#pragma unroll
                    for (int d = 0; d < 4; ++d) {
                        unsigned int q = ((vw[d] & 0x7F7F7F7Fu) + 0x7F7F7F7Fu) | vw[d];
                        cl += __popc(q & 0x80808080u);
                    }
                }
                int other = __shfl_xor(cl, 1);
                int pos = half ? other : 0;
                if (half == 0) s_cnt[row] = (unsigned char)min(cl + other, CAP);
#pragma unroll
                for (int k2 = 0; k2 < 4; ++k2) {
                    unsigned int vw[4] = {v[k2].x, v[k2].y, v[k2].z, v[k2].w};
#pragma unroll
                    for (int d = 0; d < 4; ++d) {
#pragma unroll
                        for (int b = 0; b < 4; ++b) {
                            if ((vw[d] >> (8 * b)) & 0xFFu) {
                                if (pos < CAP)
                                    s_idx[row][pos] =
                                        (unsigned short)(half * 64 + k2 * 16 + d * 4 + b);
                                ++pos;
                            }
                        }
                    }
                }
            }
        } else if (t < 64) {                        // fallback: int32 / float32
            int row = t, cnt = 0;
            for (int c = 0; c < 128; ++c) {
                bool nz;
                if (fmt & 2) nz = ((const float*)adj)[(size_t)(i0 + row) * NN + jbs + c] != 0.f;
                else         nz = ((const int*)adj)[(size_t)(i0 + row) * NN + jbs + c] != 0;
                if (nz) { if (cnt < CAP) s_idx[row][cnt] = (unsigned short)c; ++cnt; }
            }
            s_cnt[row] = (unsigned char)min(cnt, CAP);
        }
        __syncthreads();

        // ---- edge loop (all-LDS) ----
#pragma unroll
        for (int r2 = 0; r2 < 2; ++r2) {
            int row = g * 2 + r2;
            int cn = s_cnt[row];
            float sa = s_asrc[row * 4 + head];
            for (int e = 0; e < cn; ++e) {
                int jl = s_idx[row][e];
                float dv = s_adst[jl * 4 + head];
                float ev = sa + dv;
                ev = fmaxf(ev, 0.2f * ev);
                float p = __expf(ev);
                den[r2] += p;
                uint4 hv = *(const uint4*)&sH[jl * FF + l16 * 8];
                acc[r2][0] = fmaf(p, bflo(hv.x), acc[r2][0]);
                acc[r2][1] = fmaf(p, bfhi(hv.x), acc[r2][1]);
                acc[r2][2] = fmaf(p, bflo(hv.y), acc[r2][2]);
                acc[r2][3] = fmaf(p, bfhi(hv.y), acc[r2][3]);
                acc[r2][4] = fmaf(p, bflo(hv.z), acc[r2][4]);
                acc[r2][5] = fmaf(p, bfhi(hv.z), acc[r2][5]);
                acc[r2][6] = fmaf(p, bflo(hv.w), acc[r2][6]);
                acc[r2][7] = fmaf(p, bfhi(hv.w), acc[r2][7]);
            }
        }
        __syncthreads();   // protect sH/s_idx before next window's staging
    }

    // ---- write per-chunk partials ----
#pragma unroll
    for (int r2 = 0; r2 < 2; ++r2) {
        int i = i0 + g * 2 + r2;
        float4 A = {acc[r2][0], acc[r2][1], acc[r2][2], acc[r2][3]};
        float4 B = {acc[r2][4], acc[r2][5], acc[r2][6], acc[r2][7]};
        *(float4*)&num_ws[((size_t)jc * NN + i) * FF + l16 * 8]     = A;
        *(float4*)&num_ws[((size_t)jc * NN + i) * FF + l16 * 8 + 4] = B;
        if ((l16 & 3) == 0)
            den_ws[((size_t)jc * NN + i) * 4 + head] = den[r2];
    }
}

// ---------------------------------------------------------------------------
// out = sum_jc num / sum_jc den
__global__ __launch_bounds__(256) void gat_combine(const float* __restrict__ num_ws,
                                                   const float* __restrict__ den_ws,
                                                   float* __restrict__ out) {
    int id = blockIdx.x * 256 + threadIdx.x;
    int f = id & 127, i = id >> 7;
    int h = f >> 5;
    float num = 0.f, den = 0.f;
#pragma unroll
    for (int jc = 0; jc < 8; ++jc) {
        num += num_ws[((size_t)jc * NN + i) * FF + f];
        den += den_ws[((size_t)jc * NN + i) * 4 + h];
    }
    out[(size_t)i * FF + f] = (den > 0.f) ? num / den : 0.f;
}

// ---------------------------------------------------------------------------
extern "C" void kernel_launch(void* const* d_in, const int* in_sizes, int n_in,
                              void* d_out, int out_size, void* d_ws, size_t ws_size,
                              hipStream_t stream) {
    const float* x     = (const float*)d_in[0];
    const void*  adj   = d_in[1];
    const float* W     = (const float*)d_in[2];
    const float* a_src = (const float*)d_in[3];
    const float* a_dst = (const float*)d_in[4];
    float* out = (float*)d_out;

    char* ws = (char*)d_ws;
    unsigned short* hbf  = (unsigned short*)ws;                 // 1 MiB @ 0
    float*          asrc = (float*)(ws + (1u << 20));           // 64 KiB
    float*          adst = (float*)(ws + (1u << 20) + 65536);   // 64 KiB
    int*            flag = (int*)  (ws + (1u << 20) + 131072);  // 4 B (+pad)
    float*          numw = (float*)(ws + (2u << 20));           // 16 MiB @ 2M
    float*          denw = (float*)(ws + (18u << 20));          // 512 KiB @ 18M

    hipMemsetAsync(flag, 0, sizeof(int), stream);
    detect_fmt <<<64, 256, 0, stream>>>((const unsigned int*)adj, 65536, flag);
    gemm_h     <<<NN / 16, 256, 0, stream>>>(x, W, a_src, a_dst, hbf, asrc, adst);
    gat_chunk  <<<512, 512, 0, stream>>>(hbf, asrc, adst, adj, flag, numw, denw);
    gat_combine<<<2048, 256, 0, stream>>>(numw, denw, out);
}

// Round 9
// 45.625 us; speedup vs baseline: 2.7109x; 2.7109x over previous
//
#include <hip/hip_runtime.h>
#include <hip/hip_bf16.h>

#define NN 4096
#define FF 128
#define HMAX 192   // per-half edge cap (mean ~41)

__device__ __forceinline__ float bfhi(unsigned int u) { return __uint_as_float(u & 0xFFFF0000u); }
__device__ __forceinline__ float bflo(unsigned int u) { return __uint_as_float(u << 16); }

// ---------------------------------------------------------------------------
// Detect adjacency encoding from the first 256 KB (covers rows 0..3 in any
// format; self-loop at (0,0) guarantees nonzeros are seen).
// bit1 -> float32 ; else bit0 -> uint8 ; else int32.
// R8 LESSON: FETCH_SIZE could not distinguish formats (64 MB int32 adj is
// L3-resident and under-reported) — only runtime detection is trustworthy.
__global__ __launch_bounds__(256) void detect_fmt(const unsigned int* __restrict__ w,
                                                  int nwords, int* __restrict__ flag) {
    unsigned int hi = 0u, fl = 0u;
    for (int idx = blockIdx.x * blockDim.x + threadIdx.x; idx < nwords;
         idx += gridDim.x * blockDim.x) {
        unsigned int v = w[idx];
        hi |= (v & 0xFFFFFF00u);
        fl |= (v == 0x3F800000u) ? 1u : 0u;
    }
    int bits = (hi ? 1 : 0) | (fl ? 2 : 0);
    if (bits) atomicOr(flag, bits);
}

// ---------------------------------------------------------------------------
// h = x @ W^T ; emits f32 h (for attn_coef) and bf16 copy (for aggregation).
__global__ __launch_bounds__(256) void gemm_h(const float* __restrict__ x,
                                              const float* __restrict__ W,
                                              float* __restrict__ h,
                                              __hip_bfloat16* __restrict__ hbf) {
    __shared__ float xs[16][FF];
    int r0 = blockIdx.x * 16;
    const float4* xv = (const float4*)(x + (size_t)r0 * FF);
    float4* xsv = (float4*)&xs[0][0];
    for (int t = threadIdx.x; t < 16 * FF / 4; t += 256) xsv[t] = xv[t];
    __syncthreads();

    int c  = threadIdx.x & 127;
    int rr = threadIdx.x >> 7;
    float acc[8] = {0.f, 0.f, 0.f, 0.f, 0.f, 0.f, 0.f, 0.f};
    for (int k = 0; k < FF; k += 4) {
        float4 w4 = *(const float4*)&W[(size_t)c * FF + k];
#pragma unroll
        for (int r8 = 0; r8 < 8; ++r8) {
            float4 x4 = *(const float4*)&xs[rr + r8 * 2][k];
            acc[r8] += w4.x * x4.x + w4.y * x4.y + w4.z * x4.z + w4.w * x4.w;
        }
    }
#pragma unroll
    for (int r8 = 0; r8 < 8; ++r8) {
        size_t o = (size_t)(r0 + rr + r8 * 2) * FF + c;
        h[o]   = acc[r8];
        hbf[o] = __float2bfloat16(acc[r8]);
    }
}

// ---------------------------------------------------------------------------
// attn_src/dst coefficients (f32 h for precision). One wave per node.
__global__ __launch_bounds__(256) void attn_coef(const float* __restrict__ h,
                                                 const float* __restrict__ a_src,
                                                 const float* __restrict__ a_dst,
                                                 float* __restrict__ asrc,
                                                 float* __restrict__ adst) {
    int lane = threadIdx.x & 63;
    int i = blockIdx.x * 4 + (threadIdx.x >> 6);
    float h0 = h[(size_t)i * FF + lane];
    float h1 = h[(size_t)i * FF + 64 + lane];
    int d  = lane & 31;
    int hA = lane >> 5;
    int hB = hA + 2;
    float s0 = h0 * a_src[hA * 32 + d], s1 = h1 * a_src[hB * 32 + d];
    float d0 = h0 * a_dst[hA * 32 + d], d1 = h1 * a_dst[hB * 32 + d];
#pragma unroll
    for (int m = 16; m >= 1; m >>= 1) {
        s0 += __shfl_xor(s0, m); s1 += __shfl_xor(s1, m);
        d0 += __shfl_xor(d0, m); d1 += __shfl_xor(d1, m);
    }
    if (d == 0) {
        asrc[i * 4 + hA] = s0; asrc[i * 4 + hB] = s1;
        adst[i * 4 + hA] = d0; adst[i * 4 + hB] = d1;
    }
}

// ---------------------------------------------------------------------------
// 512 threads = 8 waves; 4 rows/block; 2 waves per row (one per adj half).
// Pass A: REGISTER-PRELOADED ballot-compaction for BOTH formats:
//   - 4-byte (int32/float32, fmt!=1): 8x uint4/lane = whole 8KB row-slice in
//     flight at once; word!=0 test valid for both encodings.  <-- NEW (R9):
//     this path ran in R1-R7 as a 32-iteration serial-latency loop.
//   - uint8 (fmt==1): 8x uint/lane as before.
// Fused pass: 2-stage register pipeline (R8): next 8 edges' h-rows + adst are
// issued before the current 8 are consumed (~8 outstanding gathers/wave).
// No max-subtraction: e = s+d ~ N(0,2), exp() far from f32 range.
__global__ __launch_bounds__(512, 8) void gat_agg(const unsigned short* __restrict__ hbf,
                                                  const float* __restrict__ asrc,
                                                  const float* __restrict__ adst,
                                                  const void* __restrict__ adj,
                                                  const int* __restrict__ flag,
                                                  float* __restrict__ out) {
    __shared__ int   s_idx[4][2][HMAX + 16];
    __shared__ float s_mac[4][16][8];
    __shared__ float s_mden[4][4];

    int lane = threadIdx.x & 63;
    int wv   = threadIdx.x >> 6;     // 0..7
    int r    = wv >> 1;              // row within block
    int side = wv & 1;               // adjacency half
    int i    = blockIdx.x * 4 + r;
    int fmt  = *flag;                // 0:int32  1:uint8  2/3:float32
    int* idx = s_idx[r][side];
    unsigned long long lt = (1ull << lane) - 1ull;

    // ---- Pass A: compact this half's neighbor indices ----
    int base = 0;
    if (fmt != 1) {
        // 4-byte elements (int32 or float32): word != 0 <=> edge
        const uint4* arow4 = (const uint4*)((const unsigned int*)adj +
                             (size_t)i * NN + side * 2048);
        uint4 vb[8];
#pragma unroll
        for (int it = 0; it < 8; ++it) vb[it] = arow4[it * 64 + lane];  // all in flight
#pragma unroll
        for (int it = 0; it < 8; ++it) {
            unsigned int w0 = vb[it].x, w1 = vb[it].y, w2 = vb[it].z, w3 = vb[it].w;
            unsigned long long m0 = __ballot(w0 != 0u);
            unsigned long long m1 = __ballot(w1 != 0u);
            unsigned long long m2 = __ballot(w2 != 0u);
            unsigned long long m3 = __ballot(w3 != 0u);
            int c0 = __popcll(m0), c1 = __popcll(m1), c2 = __popcll(m2);
            int p0 = base + __popcll(m0 & lt);
            int p1 = base + c0 + __popcll(m1 & lt);
            int p2 = base + c0 + c1 + __popcll(m2 & lt);
            int p3 = base + c0 + c1 + c2 + __popcll(m3 & lt);
            int jb = side * 2048 + it * 256 + lane * 4;
            if (w0 && p0 < HMAX) idx[p0] = jb;
            if (w1 && p1 < HMAX) idx[p1] = jb + 1;
            if (w2 && p2 < HMAX) idx[p2] = jb + 2;
            if (w3 && p3 < HMAX) idx[p3] = jb + 3;
            base += c0 + c1 + c2 + __popcll(m3);
        }
    } else {
        // uint8 (numpy bool)
        const unsigned int* arow =
            (const unsigned int*)((const unsigned char*)adj + (size_t)i * NN + side * 2048);
        unsigned int vb[8];
#pragma unroll
        for (int it = 0; it < 8; ++it) vb[it] = arow[it * 64 + lane];
#pragma unroll
        for (int it = 0; it < 8; ++it) {
            unsigned int v = vb[it];
            unsigned long long m0 = __ballot((v & 0x000000FFu) != 0u);
            unsigned long long m1 = __ballot((v & 0x0000FF00u) != 0u);
            unsigned long long m2 = __ballot((v & 0x00FF0000u) != 0u);
            unsigned long long m3 = __ballot((v & 0xFF000000u) != 0u);
            int c0 = __popcll(m0), c1 = __popcll(m1), c2 = __popcll(m2);
            int p0 = base + __popcll(m0 & lt);
            int p1 = base + c0 + __popcll(m1 & lt);
            int p2 = base + c0 + c1 + __popcll(m2 & lt);
            int p3 = base + c0 + c1 + c2 + __popcll(m3 & lt);
            int jb = side * 2048 + it * 256 + lane * 4;
            if ((v & 0x000000FFu) && p0 < HMAX) idx[p0] = jb;
            if ((v & 0x0000FF00u) && p1 < HMAX) idx[p1] = jb + 1;
            if ((v & 0x00FF0000u) && p2 < HMAX) idx[p2] = jb + 2;
            if ((v & 0xFF000000u) && p3 < HMAX) idx[p3] = jb + 3;
            base += c0 + c1 + c2 + __popcll(m3);
        }
    }
    int cnt = min(base, HMAX);
    if (lane < 16) idx[cnt + lane] = i;   // pads; weight forced to 0 by e<cnt
    __syncthreads();

    // ---- Fused aggregation + denominator, 2-stage pipelined ----
    int q    = lane >> 4;             // edge slot within batch of 4
    int k    = lane & 15;             // features 8k .. 8k+7
    int head = k >> 2;
    float sA = asrc[(i << 2) + head];
    const uint4* hb4 = (const uint4*)hbf;

    float a0 = 0.f, a1 = 0.f, a2 = 0.f, a3 = 0.f;
    float a4 = 0.f, a5 = 0.f, a6 = 0.f, a7 = 0.f;
    float den = 0.f;
    int cntPad = (cnt + 7) & ~7;

#define PROC(HV, DV, E) do {                                                   \
        float ev_ = sA + (DV);                                                 \
        ev_ = fmaxf(ev_, 0.2f * ev_);                                          \
        float p_ = __expf(ev_);                                                \
        p_ = ((E) < cnt) ? p_ : 0.f;                                           \
        den += p_;                                                             \
        a0 = fmaf(p_, bflo((HV).x), a0); a1 = fmaf(p_, bfhi((HV).x), a1);      \
        a2 = fmaf(p_, bflo((HV).y), a2); a3 = fmaf(p_, bfhi((HV).y), a3);      \
        a4 = fmaf(p_, bflo((HV).z), a4); a5 = fmaf(p_, bfhi((HV).z), a5);      \
        a6 = fmaf(p_, bflo((HV).w), a6); a7 = fmaf(p_, bfhi((HV).w), a7);      \
    } while (0)

    // prologue: issue batch 0 (pads make idx[0..15] always valid)
    int e0 = q, e1 = 4 + q;
    int j0 = idx[e0], j1 = idx[e1];
    uint4 hv0 = hb4[(size_t)j0 * 16 + k];
    uint4 hv1 = hb4[(size_t)j1 * 16 + k];
    float dv0 = adst[(j0 << 2) + head];
    float dv1 = adst[(j1 << 2) + head];

    for (int eb = 0; eb < cntPad; eb += 8) {
        int   ce0 = e0,  ce1 = e1;
        uint4 chv0 = hv0, chv1 = hv1;
        float cdv0 = dv0, cdv1 = dv1;
        if (eb + 8 < cntPad) {        // wave-uniform: issue NEXT batch now
            e0 = eb + 8 + q; e1 = eb + 12 + q;
            int nj0 = idx[e0], nj1 = idx[e1];
            hv0 = hb4[(size_t)nj0 * 16 + k];
            hv1 = hb4[(size_t)nj1 * 16 + k];
            dv0 = adst[(nj0 << 2) + head];
            dv1 = adst[(nj1 << 2) + head];
        }
        PROC(chv0, cdv0, ce0);        // consume current while next is in flight
        PROC(chv1, cdv1, ce1);
    }
#undef PROC

    // merge the 4 edge-quarters (lanes differing in bits 4,5 share k)
#pragma unroll
    for (int m = 16; m <= 32; m <<= 1) {
        a0 += __shfl_xor(a0, m); a1 += __shfl_xor(a1, m);
        a2 += __shfl_xor(a2, m); a3 += __shfl_xor(a3, m);
        a4 += __shfl_xor(a4, m); a5 += __shfl_xor(a5, m);
        a6 += __shfl_xor(a6, m); a7 += __shfl_xor(a7, m);
        den += __shfl_xor(den, m);
    }

    if (side == 1 && lane < 16) {
        float* mp = s_mac[r][k];
        mp[0] = a0; mp[1] = a1; mp[2] = a2; mp[3] = a3;
        mp[4] = a4; mp[5] = a5; mp[6] = a6; mp[7] = a7;
        if ((k & 3) == 0) s_mden[r][head] = den;
    }
    __syncthreads();
    if (side == 0 && lane < 16) {
        const float* mp = s_mac[r][k];
        float dtot = den + s_mden[r][head];
        float rc = (dtot > 0.f) ? 1.f / dtot : 0.f;
        float4 A = {(a0 + mp[0]) * rc, (a1 + mp[1]) * rc,
                    (a2 + mp[2]) * rc, (a3 + mp[3]) * rc};
        float4 B = {(a4 + mp[4]) * rc, (a5 + mp[5]) * rc,
                    (a6 + mp[6]) * rc, (a7 + mp[7]) * rc};
        *(float4*)&out[(size_t)i * FF + k * 8]     = A;
        *(float4*)&out[(size_t)i * FF + k * 8 + 4] = B;
    }
}

// ---------------------------------------------------------------------------
extern "C" void kernel_launch(void* const* d_in, const int* in_sizes, int n_in,
                              void* d_out, int out_size, void* d_ws, size_t ws_size,
                              hipStream_t stream) {
    const float* x     = (const float*)d_in[0];
    const void*  adj   = d_in[1];
    const float* W     = (const float*)d_in[2];
    const float* a_src = (const float*)d_in[3];
    const float* a_dst = (const float*)d_in[4];
    float* out = (float*)d_out;

    char* ws = (char*)d_ws;
    float*          h    = (float*)ws;                           // 2 MiB @ 0
    float*          asrc = (float*)(ws + (2u << 20));            // 64 KiB
    float*          adst = (float*)(ws + (2u << 20) + 65536);    // 64 KiB
    int*            flag = (int*)  (ws + (2u << 20) + 131072);   // 4 B (+pad)
    __hip_bfloat16* hbf  = (__hip_bfloat16*)(ws + (3u << 20));   // 1 MiB @ 3M

    hipMemsetAsync(flag, 0, sizeof(int), stream);
    detect_fmt<<<64, 256, 0, stream>>>((const unsigned int*)adj, 65536, flag);
    gemm_h    <<<NN / 16, 256, 0, stream>>>(x, W, h, hbf);
    attn_coef <<<NN / 4, 256, 0, stream>>>(h, a_src, a_dst, asrc, adst);
    gat_agg   <<<NN / 4, 512, 0, stream>>>((const unsigned short*)hbf, asrc, adst,
                                           adj, flag, out);
}